// Round 8
// baseline (1033.102 us; speedup 1.0000x reference)
//
#include <hip/hip_runtime.h>

constexpr int NUM_HEADS      = 32;
constexpr int HEAD_DIM       = 128;
constexpr int NUM_KV         = 8;
constexpr int GROUP          = 4;                     // query heads per kv head
constexpr int BLOCK_SIZE     = 16;
constexpr int BLOCKS_PER_SEQ = 64;
constexpr int BATCH          = 64;
constexpr int SEQ            = BLOCKS_PER_SEQ * BLOCK_SIZE;   // 1024
constexpr int KV_ROW         = NUM_KV * HEAD_DIM;             // 1024 floats / slot-row
constexpr int SPLIT          = 8;                    // flash-decode partitions
constexpr int TOK            = SEQ / SPLIT;          // 128 tokens per partition
constexpr int BLKS           = TOK / BLOCK_SIZE;     // 8 table entries per partition
constexpr int NGROUPS        = BATCH * NUM_KV;       // 512 combine groups
constexpr float SCALE        = 0.08838834764831845f;

// workspace layout (floats): unnormalized partial O, then m, then l, then
// int counters (one per (b,kvh) group) for the fused last-done combine.
constexpr size_t WS_O   = 0;
constexpr size_t WS_M   = (size_t)BATCH * NUM_KV * SPLIT * GROUP * HEAD_DIM; // 2,097,152
constexpr size_t WS_L   = WS_M + (size_t)BATCH * NUM_KV * SPLIT * GROUP;     // +16,384
constexpr size_t WS_CNT = WS_L + (size_t)BATCH * NUM_KV * SPLIT * GROUP;     // +16,384 (float idx)
constexpr size_t CNT_BYTE_OFF = WS_CNT * sizeof(float);   // 8,519,680
constexpr size_t CNT_BYTES    = (size_t)NGROUPS * sizeof(int);

// One wg (256 thr = 4 waves) per (b, kv_head, split): partial flash-attention
// (measured-best R3 structure, delivered ~6.6 TB/s). The SPLIT-way combine is
// FUSED via a last-done-workgroup pattern: after publishing its partial, each
// wg bumps a device-scope counter; the 8th wg of a group does that group's
// LSE-combine inline. No spinning (deadlock-free under any dispatch order);
// one fixed-order combine per group (deterministic output).
__global__ __launch_bounds__(256) void paged_attn_split(
    const float* __restrict__ q,            // [B, 32, 128]
    const float* __restrict__ knew,         // [B, 8, 128]
    const float* __restrict__ vnew,         // [B, 8, 128]
    const float* __restrict__ kcache,       // [4096, 16, 8, 128]
    const float* __restrict__ vcache,       // [4096, 16, 8, 128]
    const int*   __restrict__ slot_mapping, // [B]
    const int*   __restrict__ block_tables, // [B, 64]
    float*       __restrict__ ws,
    int*         __restrict__ cnt,          // [NGROUPS], zeroed per call
    float*       __restrict__ out)          // [B, 32*128]
{
    const int wg  = (int)blockIdx.x;        // ((b*KV + kvh)*SPLIT + sp)
    const int sp  = wg & (SPLIT - 1);
    const int bk  = wg >> 3;                // b*KV + kvh
    const int kvh = bk & 7;
    const int b   = bk >> 3;
    const int tid = (int)threadIdx.x;
    const int lane = tid & 63;
    const int wave = tid >> 6;

    __shared__ int   s_row[TOK];              // >=0: cache slot-row; <0: override -1-i
    __shared__ float s_p[TOK][GROUP];         // scores -> exp(score - m), [t][g]
    __shared__ float s_o[4][GROUP][HEAD_DIM]; // per-wave partial O (8 KB)
    __shared__ int   s_bt[BLKS];
    __shared__ int   s_slot[BATCH];
    __shared__ int   s_last;

    if (tid < BLKS) s_bt[tid] = block_tables[b * BLOCKS_PER_SEQ + sp * BLKS + tid];
    if (tid >= 64 && tid < 64 + BATCH) s_slot[tid - 64] = slot_mapping[tid - 64];
    __syncthreads();

    // Token -> source row. Reference scatters fresh k/v into the cache before
    // the gather; we must not mutate inputs, so redirect reads instead.
    if (tid < TOK) {
        int slot = s_bt[tid >> 4] * BLOCK_SIZE + (tid & 15);
        int r = slot;
        #pragma unroll
        for (int i = 0; i < BATCH; ++i)
            if (s_slot[i] == slot) r = -1 - i;
        s_row[tid] = r;
    }

    const int h0 = kvh * GROUP;
    const size_t hoff = (size_t)kvh * HEAD_DIM;
    const int sub = lane >> 4;              // token sub-slot within wave (0..3)
    const int sl  = lane & 15;              // 16 lanes cooperate per token

    float4 qa[GROUP], qb[GROUP];            // q[g][sl*8 .. sl*8+8)
    #pragma unroll
    for (int g = 0; g < GROUP; ++g) {
        const float* qp = q + ((size_t)b * NUM_HEADS + h0 + g) * HEAD_DIM + sl * 8;
        qa[g] = *reinterpret_cast<const float4*>(qp);
        qb[g] = *reinterpret_cast<const float4*>(qp + 4);
    }
    __syncthreads();

    // ---- Phase 1: scores. 4 tokens/wave/iter, 16 lanes per token, f4 loads.
    #pragma unroll
    for (int t = wave * 4 + sub; t < TOK; t += 16) {
        int r = s_row[t];
        const float* krow = (r >= 0)
            ? kcache + (size_t)r * KV_ROW + hoff
            : knew   + (size_t)(-1 - r) * KV_ROW + hoff;
        float4 ka = *reinterpret_cast<const float4*>(krow + sl * 8);
        float4 kb = *reinterpret_cast<const float4*>(krow + sl * 8 + 4);
        float p[GROUP];
        #pragma unroll
        for (int g = 0; g < GROUP; ++g) {
            p[g] = qa[g].x * ka.x + qa[g].y * ka.y + qa[g].z * ka.z + qa[g].w * ka.w
                 + qb[g].x * kb.x + qb[g].y * kb.y + qb[g].z * kb.z + qb[g].w * kb.w;
        }
        #pragma unroll
        for (int off = 1; off < 16; off <<= 1) {
            #pragma unroll
            for (int g = 0; g < GROUP; ++g) p[g] += __shfl_xor(p[g], off);
        }
        if (sl == 0) {
            #pragma unroll
            for (int g = 0; g < GROUP; ++g) s_p[t][g] = p[g] * SCALE;
        }
    }
    __syncthreads();

    // ---- Phase 2: partial softmax stats over TOK=128 (wave = head) ----
    {
        const int g = wave;
        float v0 = s_p[lane][g], v1 = s_p[lane + 64][g];
        float m = fmaxf(v0, v1);
        #pragma unroll
        for (int off = 32; off; off >>= 1) m = fmaxf(m, __shfl_xor(m, off));
        float e0 = __expf(v0 - m), e1 = __expf(v1 - m);
        s_p[lane][g] = e0;
        s_p[lane + 64][g] = e1;
        float sum = e0 + e1;
        #pragma unroll
        for (int off = 32; off; off >>= 1) sum += __shfl_xor(sum, off);
        if (lane == 0) {
            ws[WS_M + (size_t)wg * GROUP + g] = m;
            ws[WS_L + (size_t)wg * GROUP + g] = sum;
        }
    }
    __syncthreads();

    // ---- Phase 3: unnormalized partial O. Tokens partitioned across waves
    // (no duplicate loads); half-wave per V row, float4/lane; acc = 4 dims x
    // 4 heads in registers; cross-half shfl + cross-wave LDS reduce at end.
    {
        const int half = lane >> 5;         // which of 2 tokens this iter
        const int dl   = lane & 31;         // dim-lane: dims [dl*4, dl*4+4)
        float4 a0 = {0,0,0,0}, a1 = a0, a2 = a0, a3 = a0;
        #pragma unroll 8
        for (int i = 0; i < TOK / 8; ++i) { // 16 iters, 2 tokens/iter/wave
            int t = wave * (TOK / 4) + i * 2 + half;
            int r = s_row[t];
            const float* vrow = (r >= 0)
                ? vcache + (size_t)r * KV_ROW + hoff
                : vnew   + (size_t)(-1 - r) * KV_ROW + hoff;
            float4 vv = *reinterpret_cast<const float4*>(vrow + dl * 4);
            float4 pv = *reinterpret_cast<const float4*>(&s_p[t][0]); // broadcast
            a0.x += pv.x * vv.x; a0.y += pv.x * vv.y; a0.z += pv.x * vv.z; a0.w += pv.x * vv.w;
            a1.x += pv.y * vv.x; a1.y += pv.y * vv.y; a1.z += pv.y * vv.z; a1.w += pv.y * vv.w;
            a2.x += pv.z * vv.x; a2.y += pv.z * vv.y; a2.z += pv.z * vv.z; a2.w += pv.z * vv.w;
            a3.x += pv.w * vv.x; a3.y += pv.w * vv.y; a3.z += pv.w * vv.z; a3.w += pv.w * vv.w;
        }
        // combine the two token-halves: lane d gets lane d+32's partial
        #define RED4(A) A.x += __shfl_xor(A.x, 32); A.y += __shfl_xor(A.y, 32); \
                        A.z += __shfl_xor(A.z, 32); A.w += __shfl_xor(A.w, 32);
        RED4(a0) RED4(a1) RED4(a2) RED4(a3)
        #undef RED4
        if (half == 0) {
            *reinterpret_cast<float4*>(&s_o[wave][0][dl * 4]) = a0;
            *reinterpret_cast<float4*>(&s_o[wave][1][dl * 4]) = a1;
            *reinterpret_cast<float4*>(&s_o[wave][2][dl * 4]) = a2;
            *reinterpret_cast<float4*>(&s_o[wave][3][dl * 4]) = a3;
        }
    }
    __syncthreads();

    // cross-wave reduce + store partial O: thread owns (g=wave, 2 dims)
    {
        const int g = wave;
        const int d = lane * 2;
        float ox = 0.f, oy = 0.f;
        #pragma unroll
        for (int u = 0; u < 4; ++u) {
            ox += s_o[u][g][d];
            oy += s_o[u][g][d + 1];
        }
        *reinterpret_cast<float2*>(
            ws + WS_O + ((size_t)wg * GROUP + g) * HEAD_DIM + d) = make_float2(ox, oy);
    }

    // ---- Fused combine: last wg of this (b,kvh) group does the 8-way LSE
    // combine. Release: partial stores -> threadfence -> device-scope atomic.
    __threadfence();
    if (tid == 0) s_last = (atomicAdd(&cnt[bk], 1) == SPLIT - 1) ? 1 : 0;
    __syncthreads();
    if (!s_last) return;
    __threadfence();   // acquire side: order partial loads after the atomic

    for (int idx = tid; idx < GROUP * HEAD_DIM; idx += 256) {
        const int g = idx >> 7;             // / HEAD_DIM
        const int d = idx & (HEAD_DIM - 1);
        float m[SPLIT], mstar = -1e30f;
        #pragma unroll
        for (int s = 0; s < SPLIT; ++s) {
            m[s] = ws[WS_M + ((size_t)bk * SPLIT + s) * GROUP + g];
            mstar = fmaxf(mstar, m[s]);
        }
        float L = 0.f, acc = 0.f;
        #pragma unroll
        for (int s = 0; s < SPLIT; ++s) {
            float wgt = __expf(m[s] - mstar);
            L   += wgt * ws[WS_L + ((size_t)bk * SPLIT + s) * GROUP + g];
            acc += wgt * ws[WS_O + (((size_t)bk * SPLIT + s) * GROUP + g) * HEAD_DIM + d];
        }
        out[((size_t)b * NUM_HEADS + kvh * GROUP + g) * HEAD_DIM + d] = acc / L;
    }
}

extern "C" void kernel_launch(void* const* d_in, const int* in_sizes, int n_in,
                              void* d_out, int out_size, void* d_ws, size_t ws_size,
                              hipStream_t stream) {
    const float* q    = (const float*)d_in[0];
    const float* knew = (const float*)d_in[1];
    const float* vnew = (const float*)d_in[2];
    const float* kc   = (const float*)d_in[3];
    const float* vc   = (const float*)d_in[4];
    const int*   slot = (const int*)d_in[5];
    const int*   bt   = (const int*)d_in[6];
    float* out = (float*)d_out;
    float* ws  = (float*)d_ws;   // needs ~8.6 MB
    int*   cnt = (int*)((char*)d_ws + CNT_BYTE_OFF);

    // zero the per-group completion counters (graph-capturable memset)
    hipMemsetAsync(cnt, 0, CNT_BYTES, stream);

    hipLaunchKernelGGL(paged_attn_split, dim3(BATCH * NUM_KV * SPLIT), dim3(256),
                       0, stream, q, knew, vnew, kc, vc, slot, bt, ws, cnt, out);
}

// Round 9
// 85.921 us; speedup vs baseline: 12.0239x; 12.0239x over previous
//
#include <hip/hip_runtime.h>

constexpr int NUM_HEADS      = 32;
constexpr int HEAD_DIM       = 128;
constexpr int NUM_KV         = 8;
constexpr int GROUP          = 4;                     // query heads per kv head
constexpr int BLOCK_SIZE     = 16;
constexpr int BLOCKS_PER_SEQ = 64;
constexpr int BATCH          = 64;
constexpr int SEQ            = BLOCKS_PER_SEQ * BLOCK_SIZE;   // 1024
constexpr int KV_ROW         = NUM_KV * HEAD_DIM;             // 1024 floats / slot-row
constexpr int SPLIT          = 8;                    // flash-decode partitions
constexpr int TOK            = SEQ / SPLIT;          // 128 tokens per partition
constexpr int BLKS           = TOK / BLOCK_SIZE;     // 8 table entries per partition
constexpr float SCALE        = 0.08838834764831845f;

// workspace layout (floats): unnormalized partial O, then m, then l
constexpr size_t WS_O = 0;
constexpr size_t WS_M = (size_t)BATCH * NUM_KV * SPLIT * GROUP * HEAD_DIM; // 2,097,152
constexpr size_t WS_L = WS_M + (size_t)BATCH * NUM_KV * SPLIT * GROUP;     // +16,384

// One wg (256 thr = 4 waves) per (b, kv_head, split): partial flash-attention.
// Measured-best structure (R3/R7: 85.9/86.2us). Delivered load BW ~6.6 TB/s
// (512 MB logical / ~78us split) >= the 6.29 TB/s streaming ceiling, with L3
// supplying cross-batch block re-reads (FETCH 263 MB = L3-residency floor).
// Falsified levers: barrier removal (R4 =), deeper MLP (R5 =), 64KB DRAM
// granules (R6 -12%), fused last-done combine (R8 -12x: device-scope fences
// cause cross-XCD L2 writeback storms on gfx950 -- never fence in hot path).
__global__ __launch_bounds__(256) void paged_attn_split(
    const float* __restrict__ q,            // [B, 32, 128]
    const float* __restrict__ knew,         // [B, 8, 128]
    const float* __restrict__ vnew,         // [B, 8, 128]
    const float* __restrict__ kcache,       // [4096, 16, 8, 128]
    const float* __restrict__ vcache,       // [4096, 16, 8, 128]
    const int*   __restrict__ slot_mapping, // [B]
    const int*   __restrict__ block_tables, // [B, 64]
    float*       __restrict__ ws)
{
    const int wg  = (int)blockIdx.x;        // ((b*KV + kvh)*SPLIT + sp)
    const int sp  = wg & (SPLIT - 1);
    const int bk  = wg >> 3;                // b*KV + kvh
    const int kvh = bk & 7;
    const int b   = bk >> 3;
    const int tid = (int)threadIdx.x;
    const int lane = tid & 63;
    const int wave = tid >> 6;

    __shared__ int   s_row[TOK];              // >=0: cache slot-row; <0: override -1-i
    __shared__ float s_p[TOK][GROUP];         // scores -> exp(score - m), [t][g]
    __shared__ float s_o[4][GROUP][HEAD_DIM]; // per-wave partial O (8 KB)
    __shared__ int   s_bt[BLKS];
    __shared__ int   s_slot[BATCH];

    if (tid < BLKS) s_bt[tid] = block_tables[b * BLOCKS_PER_SEQ + sp * BLKS + tid];
    if (tid >= 64 && tid < 64 + BATCH) s_slot[tid - 64] = slot_mapping[tid - 64];
    __syncthreads();

    // Token -> source row. Reference scatters fresh k/v into the cache before
    // the gather; we must not mutate inputs, so redirect reads instead.
    if (tid < TOK) {
        int slot = s_bt[tid >> 4] * BLOCK_SIZE + (tid & 15);
        int r = slot;
        #pragma unroll
        for (int i = 0; i < BATCH; ++i)
            if (s_slot[i] == slot) r = -1 - i;
        s_row[tid] = r;
    }

    const int h0 = kvh * GROUP;
    const size_t hoff = (size_t)kvh * HEAD_DIM;
    const int sub = lane >> 4;              // token sub-slot within wave (0..3)
    const int sl  = lane & 15;              // 16 lanes cooperate per token

    float4 qa[GROUP], qb[GROUP];            // q[g][sl*8 .. sl*8+8)
    #pragma unroll
    for (int g = 0; g < GROUP; ++g) {
        const float* qp = q + ((size_t)b * NUM_HEADS + h0 + g) * HEAD_DIM + sl * 8;
        qa[g] = *reinterpret_cast<const float4*>(qp);
        qb[g] = *reinterpret_cast<const float4*>(qp + 4);
    }
    __syncthreads();

    // ---- Phase 1: scores. 4 tokens/wave/iter, 16 lanes per token, f4 loads.
    #pragma unroll
    for (int t = wave * 4 + sub; t < TOK; t += 16) {
        int r = s_row[t];
        const float* krow = (r >= 0)
            ? kcache + (size_t)r * KV_ROW + hoff
            : knew   + (size_t)(-1 - r) * KV_ROW + hoff;
        float4 ka = *reinterpret_cast<const float4*>(krow + sl * 8);
        float4 kb = *reinterpret_cast<const float4*>(krow + sl * 8 + 4);
        float p[GROUP];
        #pragma unroll
        for (int g = 0; g < GROUP; ++g) {
            p[g] = qa[g].x * ka.x + qa[g].y * ka.y + qa[g].z * ka.z + qa[g].w * ka.w
                 + qb[g].x * kb.x + qb[g].y * kb.y + qb[g].z * kb.z + qb[g].w * kb.w;
        }
        #pragma unroll
        for (int off = 1; off < 16; off <<= 1) {
            #pragma unroll
            for (int g = 0; g < GROUP; ++g) p[g] += __shfl_xor(p[g], off);
        }
        if (sl == 0) {
            #pragma unroll
            for (int g = 0; g < GROUP; ++g) s_p[t][g] = p[g] * SCALE;
        }
    }
    __syncthreads();

    // ---- Phase 2: partial softmax stats over TOK=128 (wave = head) ----
    {
        const int g = wave;
        float v0 = s_p[lane][g], v1 = s_p[lane + 64][g];
        float m = fmaxf(v0, v1);
        #pragma unroll
        for (int off = 32; off; off >>= 1) m = fmaxf(m, __shfl_xor(m, off));
        float e0 = __expf(v0 - m), e1 = __expf(v1 - m);
        s_p[lane][g] = e0;
        s_p[lane + 64][g] = e1;
        float sum = e0 + e1;
        #pragma unroll
        for (int off = 32; off; off >>= 1) sum += __shfl_xor(sum, off);
        if (lane == 0) {
            ws[WS_M + (size_t)wg * GROUP + g] = m;
            ws[WS_L + (size_t)wg * GROUP + g] = sum;
        }
    }
    __syncthreads();

    // ---- Phase 3: unnormalized partial O. Tokens partitioned across waves
    // (no duplicate loads); half-wave per V row, float4/lane; acc = 4 dims x
    // 4 heads in registers; cross-half shfl + cross-wave LDS reduce at end.
    {
        const int half = lane >> 5;         // which of 2 tokens this iter
        const int dl   = lane & 31;         // dim-lane: dims [dl*4, dl*4+4)
        float4 a0 = {0,0,0,0}, a1 = a0, a2 = a0, a3 = a0;
        #pragma unroll 8
        for (int i = 0; i < TOK / 8; ++i) { // 16 iters, 2 tokens/iter/wave
            int t = wave * (TOK / 4) + i * 2 + half;
            int r = s_row[t];
            const float* vrow = (r >= 0)
                ? vcache + (size_t)r * KV_ROW + hoff
                : vnew   + (size_t)(-1 - r) * KV_ROW + hoff;
            float4 vv = *reinterpret_cast<const float4*>(vrow + dl * 4);
            float4 pv = *reinterpret_cast<const float4*>(&s_p[t][0]); // broadcast
            a0.x += pv.x * vv.x; a0.y += pv.x * vv.y; a0.z += pv.x * vv.z; a0.w += pv.x * vv.w;
            a1.x += pv.y * vv.x; a1.y += pv.y * vv.y; a1.z += pv.y * vv.z; a1.w += pv.y * vv.w;
            a2.x += pv.z * vv.x; a2.y += pv.z * vv.y; a2.z += pv.z * vv.z; a2.w += pv.z * vv.w;
            a3.x += pv.w * vv.x; a3.y += pv.w * vv.y; a3.z += pv.w * vv.z; a3.w += pv.w * vv.w;
        }
        // combine the two token-halves: lane d gets lane d+32's partial
        #define RED4(A) A.x += __shfl_xor(A.x, 32); A.y += __shfl_xor(A.y, 32); \
                        A.z += __shfl_xor(A.z, 32); A.w += __shfl_xor(A.w, 32);
        RED4(a0) RED4(a1) RED4(a2) RED4(a3)
        #undef RED4
        if (half == 0) {
            *reinterpret_cast<float4*>(&s_o[wave][0][dl * 4]) = a0;
            *reinterpret_cast<float4*>(&s_o[wave][1][dl * 4]) = a1;
            *reinterpret_cast<float4*>(&s_o[wave][2][dl * 4]) = a2;
            *reinterpret_cast<float4*>(&s_o[wave][3][dl * 4]) = a3;
        }
    }
    __syncthreads();

    // cross-wave reduce + store partial O: thread owns (g=wave, 2 dims)
    {
        const int g = wave;
        const int d = lane * 2;
        float ox = 0.f, oy = 0.f;
        #pragma unroll
        for (int w = 0; w < 4; ++w) {
            ox += s_o[w][g][d];
            oy += s_o[w][g][d + 1];
        }
        *reinterpret_cast<float2*>(
            ws + WS_O + ((size_t)wg * GROUP + g) * HEAD_DIM + d) = make_float2(ox, oy);
    }
}

// Log-sum-exp combine of SPLIT partials per (b, kvh, g). 2048 blocks x 128 thr.
__global__ __launch_bounds__(128) void paged_attn_combine(
    const float* __restrict__ ws, float* __restrict__ out)
{
    const int hb  = (int)blockIdx.x;        // (b*KV+kvh)*GROUP + g
    const int g   = hb & 3;
    const int bk  = hb >> 2;
    const int kvh = bk & 7;
    const int b   = bk >> 3;
    const int d   = (int)threadIdx.x;

    float m[SPLIT];
    float mstar = -1e30f;
    #pragma unroll
    for (int s = 0; s < SPLIT; ++s) {
        m[s] = ws[WS_M + ((size_t)(bk * SPLIT + s) * GROUP) + g];
        mstar = fmaxf(mstar, m[s]);
    }
    float L = 0.f, acc = 0.f;
    #pragma unroll
    for (int s = 0; s < SPLIT; ++s) {
        float w = __expf(m[s] - mstar);
        L   += w * ws[WS_L + ((size_t)(bk * SPLIT + s) * GROUP) + g];
        acc += w * ws[WS_O + ((size_t)(bk * SPLIT + s) * GROUP + g) * HEAD_DIM + d];
    }
    out[((size_t)b * NUM_HEADS + kvh * GROUP + g) * HEAD_DIM + d] = acc / L;
}

extern "C" void kernel_launch(void* const* d_in, const int* in_sizes, int n_in,
                              void* d_out, int out_size, void* d_ws, size_t ws_size,
                              hipStream_t stream) {
    const float* q    = (const float*)d_in[0];
    const float* knew = (const float*)d_in[1];
    const float* vnew = (const float*)d_in[2];
    const float* kc   = (const float*)d_in[3];
    const float* vc   = (const float*)d_in[4];
    const int*   slot = (const int*)d_in[5];
    const int*   bt   = (const int*)d_in[6];
    float* out = (float*)d_out;
    float* ws  = (float*)d_ws;   // needs 8.5 MB

    hipLaunchKernelGGL(paged_attn_split, dim3(BATCH * NUM_KV * SPLIT), dim3(256),
                       0, stream, q, knew, vnew, kc, vc, slot, bt, ws);
    hipLaunchKernelGGL(paged_attn_combine, dim3(BATCH * NUM_KV * GROUP), dim3(128),
                       0, stream, ws, out);
}